// Round 6
// baseline (358.304 us; speedup 1.0000x reference)
//
#include <hip/hip_runtime.h>
#include <math.h>

// Problem constants (fixed by the reference)
#define BB 32
#define TT_SEQ 2048
#define EPROJS 512
#define ATT 512
#define NCH 32
#define FILT 100
#define KCONV 201   // 2*FILT+1
#define G4 2048     // 4*ATT

typedef unsigned short ushort_t;
typedef unsigned int uint_t;
typedef __attribute__((ext_vector_type(8))) short bf16x8_t;
typedef __attribute__((ext_vector_type(4))) float f32x4_t;

__device__ inline ushort_t f2bf(float f) {
    uint_t u = __float_as_uint(f);
    uint_t r = (u + 0x7fffu + ((u >> 16) & 1u)) >> 16;   // RNE
    return (ushort_t)r;
}

__device__ inline float tanh_fast(float x) {
    float e = __expf(2.0f * x);
    return 1.0f - 2.0f / (e + 1.0f);   // exact at +/-inf saturation
}

// ---------------------------------------------------------------------------
// K_pre: branched grid. Blocks 0..1023: location conv+relu+maxpool -> feat.
// Blocks 1024..1087: V_w transpose->bf16 + add_vec bias init + score zeroing.
// ---------------------------------------------------------------------------
__global__ __launch_bounds__(256) void k_pre(const float* __restrict__ att_prev,
                                             const float* __restrict__ conv_w,
                                             float* __restrict__ feat,
                                             const float* __restrict__ vw,
                                             ushort_t* __restrict__ vwt,
                                             const float* __restrict__ U_b,
                                             const float* __restrict__ W_b,
                                             const float* __restrict__ V_b,
                                             float* __restrict__ add_vec,
                                             float* __restrict__ score) {
    __shared__ __align__(16) float shbuf[64 * 65];   // 16.6 KB, both branches
    __shared__ float red[4];
    if (blockIdx.x < 1024) {
        // ---- conv branch: sliding register window, 8 t per thread ----
        int b = blockIdx.x >> 5;
        int c = blockIdx.x & 31;
        float* row = shbuf;                          // needs 2256 floats
        for (int i = threadIdx.x; i < TT_SEQ + 2 * FILT + 8; i += 256) {
            int t = i - FILT;
            row[i] = (t >= 0 && t < TT_SEQ) ? att_prev[b * TT_SEQ + t] : 0.0f;
        }
        __syncthreads();
        const float* cw = conv_w + c * KCONV;        // block-uniform -> scalar loads
        int t0 = threadIdx.x * 8;
        float acc[8] = {0.f, 0.f, 0.f, 0.f, 0.f, 0.f, 0.f, 0.f};
        float4 r0 = *(const float4*)(row + t0);
        float4 r1 = *(const float4*)(row + t0 + 4);
        float r[8] = {r0.x, r0.y, r0.z, r0.w, r1.x, r1.y, r1.z, r1.w};
        for (int k = 0; k < 200; k += 8) {
            float4 n0 = *(const float4*)(row + t0 + k + 8);
            float4 n1 = *(const float4*)(row + t0 + k + 12);
            float nn[8] = {n0.x, n0.y, n0.z, n0.w, n1.x, n1.y, n1.z, n1.w};
            #pragma unroll
            for (int kk = 0; kk < 8; ++kk) {
                float w = cw[k + kk];
                #pragma unroll
                for (int i = 0; i < 8; ++i) {
                    float rv = (kk + i < 8) ? r[kk + i] : nn[kk + i - 8];
                    acc[i] = fmaf(w, rv, acc[i]);
                }
            }
            #pragma unroll
            for (int i = 0; i < 8; ++i) r[i] = nn[i];
        }
        float wlast = cw[200];
        #pragma unroll
        for (int i = 0; i < 8; ++i) acc[i] = fmaf(wlast, r[i], acc[i]);
        float m = 0.0f;  // relu floor
        #pragma unroll
        for (int i = 0; i < 8; ++i) m = fmaxf(m, acc[i]);
        #pragma unroll
        for (int off = 32; off; off >>= 1) m = fmaxf(m, __shfl_xor(m, off, 64));
        if ((threadIdx.x & 63) == 0) red[threadIdx.x >> 6] = m;
        __syncthreads();
        if (threadIdx.x == 0) {
            m = fmaxf(fmaxf(red[0], red[1]), fmaxf(red[2], red[3]));
            feat[b * NCH + c] = m;
        }
    } else {
        // ---- cvtw branch: V_w transpose->bf16; bias init; score zero ----
        int id = blockIdx.x - 1024;                  // 0..63
        int eb = (id & 7) * 64, ab = (id >> 3) * 64;
        float (*tile)[65] = (float (*)[65])shbuf;
        for (int it = 0; it < 16; ++it) {
            int idx = threadIdx.x + it * 256;
            int r = idx >> 6, c = idx & 63;
            tile[r][c] = vw[(size_t)(eb + r) * ATT + ab + c];
        }
        __syncthreads();
        for (int it = 0; it < 16; ++it) {
            int idx = threadIdx.x + it * 256;
            int r = idx >> 6, c = idx & 63;
            vwt[(size_t)(ab + r) * EPROJS + eb + c] = f2bf(tile[c][r]);
        }
        int i = id * 256 + threadIdx.x;              // 0..16383
        int a = i & 511;
        add_vec[i] = U_b[a] + W_b[a] + V_b[a];
        // zero score: 64 blocks x 256 threads x 1 float4 = 65536 floats
        ((float4*)score)[id * 256 + threadIdx.x] = (float4){0.f, 0.f, 0.f, 0.f};
    }
}

// ---------------------------------------------------------------------------
// K2: gates[b][j] = biases + feat@W_ih[j,:] + att_h@W_hh[j,:]
// ---------------------------------------------------------------------------
#define HP 518
__global__ __launch_bounds__(256) void k_gates(const float* __restrict__ feat,
                                               const float* __restrict__ att_h,
                                               const float* __restrict__ W_ih,
                                               const float* __restrict__ W_hh,
                                               const float* __restrict__ b_ih,
                                               const float* __restrict__ b_hh,
                                               float* __restrict__ gates) {
    __shared__ float hsh[32 * HP];
    __shared__ float fsh[32 * 33];
    int tid = threadIdx.x;
    for (int i = tid; i < 32 * 512; i += 256) {
        int r = i >> 9, c = i & 511;
        hsh[r * HP + c] = att_h[i];
    }
    for (int i = tid; i < 1024; i += 256) fsh[(i >> 5) * 33 + (i & 31)] = feat[i];
    __syncthreads();
    int jl = tid >> 5, b = tid & 31;
    int j = blockIdx.x * 8 + jl;
    float acc = b_ih[j] + b_hh[j];
    const float4* wi = (const float4*)(W_ih + (size_t)j * NCH);
    #pragma unroll
    for (int k4 = 0; k4 < 8; ++k4) {
        float4 w = wi[k4];
        const float* f = fsh + b * 33 + k4 * 4;
        acc = fmaf(w.x, f[0], acc);
        acc = fmaf(w.y, f[1], acc);
        acc = fmaf(w.z, f[2], acc);
        acc = fmaf(w.w, f[3], acc);
    }
    const float4* wh = (const float4*)(W_hh + (size_t)j * ATT);
    float a0 = 0.f, a1 = 0.f, a2 = 0.f, a3 = 0.f;
    #pragma unroll 8
    for (int k4 = 0; k4 < 128; ++k4) {
        float4 w = wh[k4];
        float2 h0 = *(const float2*)(hsh + b * HP + k4 * 4);
        float2 h1 = *(const float2*)(hsh + b * HP + k4 * 4 + 2);
        a0 = fmaf(w.x, h0.x, a0);
        a1 = fmaf(w.y, h0.y, a1);
        a2 = fmaf(w.z, h1.x, a2);
        a3 = fmaf(w.w, h1.y, a3);
    }
    gates[(size_t)b * G4 + j] = acc + ((a0 + a1) + (a2 + a3));
}

// ---------------------------------------------------------------------------
// K3: fused LSTM pointwise + add_vec split-K GEMM.
// ---------------------------------------------------------------------------
__global__ __launch_bounds__(256) void k_hz(const float* __restrict__ gates,
                                            const float* __restrict__ att_c,
                                            const float* __restrict__ dec_z,
                                            const float* __restrict__ U_w,
                                            const float* __restrict__ W_w,
                                            float* __restrict__ h_out,
                                            float* __restrict__ c_out,
                                            float* __restrict__ add_vec) {
    int a0 = blockIdx.x * 32;
    int k0 = blockIdx.y * 64;
    __shared__ float zsh[32 * 65];
    __shared__ float hsh[32 * 65];
    __shared__ float us[64 * 33];
    __shared__ float ws2[64 * 33];
    int tid = threadIdx.x;
    for (int i = tid; i < 2048; i += 256) {
        int b = i >> 6, d = i & 63;
        int idx = b * ATT + k0 + d;
        const float* g = gates + (size_t)b * G4 + k0 + d;
        float ig = g[0], fg = g[ATT], gg = g[2 * ATT], og = g[3 * ATT];
        float si = 1.0f / (1.0f + expf(-ig));
        float sf = 1.0f / (1.0f + expf(-fg));
        float so = 1.0f / (1.0f + expf(-og));
        float cn = sf * att_c[idx] + si * tanhf(gg);
        float hn = so * tanhf(cn);
        hsh[b * 65 + d] = hn;
        if (blockIdx.x == 0) { c_out[idx] = cn; h_out[idx] = hn; }
        zsh[b * 65 + d] = dec_z[idx];
        int dr = i >> 5, c = i & 31;
        us[dr * 33 + c] = U_w[(size_t)(k0 + dr) * ATT + a0 + c];
        ws2[dr * 33 + c] = W_w[(size_t)(k0 + dr) * ATT + a0 + c];
    }
    __syncthreads();
    int al = tid >> 5, b = tid & 31;
    float acc[4] = {0.f, 0.f, 0.f, 0.f};
    for (int d = 0; d < 64; ++d) {
        float zv = zsh[b * 65 + d];
        float hv = hsh[b * 65 + d];
        #pragma unroll
        for (int m = 0; m < 4; ++m) {
            int a = al + 8 * m;
            acc[m] = fmaf(zv, us[d * 33 + a], acc[m]);
            acc[m] = fmaf(hv, ws2[d * 33 + a], acc[m]);
        }
    }
    #pragma unroll
    for (int m = 0; m < 4; ++m)
        atomicAdd(&add_vec[(size_t)b * ATT + a0 + al + 8 * m], acc[m]);
}

// ---------------------------------------------------------------------------
// K4: fused bf16 MFMA GEMM + score epilogue, 128x128 tile (m97 shape).
// 256 threads = 4 waves 2x2, per-wave 64x64, acc[4][4] (64 acc regs ->
// 2-3 blocks/CU vs 1 for the full-N variant). BK=64. A read fp32 from enc,
// converted to bf16 in-register during staging; B via global_load_lds.
// grid = (512 m-tiles, 4 n-tiles) = 2048 blocks -> 8 blocks/CU queued.
// ---------------------------------------------------------------------------
__global__ __launch_bounds__(256) void k_gemm_score3(
        const float* __restrict__ enc,
        const ushort_t* __restrict__ Btbf,
        const float* __restrict__ add_vec,
        const float* __restrict__ g_w,
        const int* __restrict__ lens,
        float* __restrict__ score) {
    int mtile = blockIdx.x;
    int b = mtile >> 4;
    int t0 = (mtile & 15) * 128;
    if (t0 >= lens[b]) return;          // fully masked tile: score never read
    int n0 = blockIdx.y * 128;

    __shared__ __align__(16) ushort_t sA[128 * 64];   // 16 KB
    __shared__ __align__(16) ushort_t sB[128 * 64];   // 16 KB
    __shared__ float sred[128];

    int tid = threadIdx.x;
    int lane = tid & 63;
    int wave = tid >> 6;
    int wm = wave >> 1, wn = wave & 1;
    int q = lane >> 4, l15 = lane & 15;

    if (tid < 128) sred[tid] = 0.0f;

    const float* Ag = enc + (size_t)mtile * 128 * EPROJS;
    const ushort_t* Bg = Btbf + (size_t)n0 * EPROJS;

    f32x4_t acc[4][4];
    #pragma unroll
    for (int i = 0; i < 4; ++i)
        #pragma unroll
        for (int j = 0; j < 4; ++j) acc[i][j] = (f32x4_t){0.f, 0.f, 0.f, 0.f};

    for (int kc = 0; kc < 8; ++kc) {
        __syncthreads();
        // B tile via DMA: 128 rows x 8 kq-groups = 1024 groups of 16 B
        #pragma unroll
        for (int it = 0; it < 4; ++it) {
            int g = tid + it * 256;
            int n = g >> 3;
            int kq = g & 7;
            int kqs = kq ^ (n & 7);
            __builtin_amdgcn_global_load_lds(
                (const __attribute__((address_space(1))) void*)(Bg + (size_t)n * EPROJS + kc * 64 + kqs * 8),
                (__attribute__((address_space(3))) void*)(sB + g * 8), 16, 0, 0);
        }
        // A tile: fp32 load -> bf16 RNE -> ds_write_b128 (overlaps B DMA)
        #pragma unroll
        for (int it = 0; it < 4; ++it) {
            int g = tid + it * 256;
            int m = g >> 3;
            int kq = g & 7;
            int kqs = kq ^ (m & 7);
            const float* src = Ag + (size_t)m * EPROJS + kc * 64 + kqs * 8;
            float4 v0 = *(const float4*)(src);
            float4 v1 = *(const float4*)(src + 4);
            bf16x8_t o;
            o[0] = (short)f2bf(v0.x); o[1] = (short)f2bf(v0.y);
            o[2] = (short)f2bf(v0.z); o[3] = (short)f2bf(v0.w);
            o[4] = (short)f2bf(v1.x); o[5] = (short)f2bf(v1.y);
            o[6] = (short)f2bf(v1.z); o[7] = (short)f2bf(v1.w);
            *(bf16x8_t*)(sA + g * 8) = o;
        }
        __syncthreads();                       // drains vmcnt + lgkmcnt
        #pragma unroll
        for (int s = 0; s < 2; ++s) {
            bf16x8_t af[4], bfr[4];
            int kq = s * 4 + q;
            #pragma unroll
            for (int i = 0; i < 4; ++i) {
                int m = wm * 64 + i * 16 + l15;
                af[i] = *(const bf16x8_t*)(sA + (m * 8 + (kq ^ (m & 7))) * 8);
            }
            #pragma unroll
            for (int j = 0; j < 4; ++j) {
                int n = wn * 64 + j * 16 + l15;
                bfr[j] = *(const bf16x8_t*)(sB + (n * 8 + (kq ^ (n & 7))) * 8);
            }
            #pragma unroll
            for (int i = 0; i < 4; ++i)
                #pragma unroll
                for (int j = 0; j < 4; ++j)
                    acc[i][j] = __builtin_amdgcn_mfma_f32_16x16x32_bf16(af[i], bfr[j], acc[i][j], 0, 0, 0);
        }
    }

    // ---- epilogue: partial scores over this 128-col slice -----------------
    float g4[4], av4[4];
    #pragma unroll
    for (int j = 0; j < 4; ++j) {
        int a = n0 + wn * 64 + j * 16 + l15;
        g4[j] = g_w[a];
        av4[j] = add_vec[b * ATT + a];
    }
    float s_ir[4][4];
    #pragma unroll
    for (int i = 0; i < 4; ++i) {
        #pragma unroll
        for (int r = 0; r < 4; ++r) {
            float s = 0.0f;
            #pragma unroll
            for (int j = 0; j < 4; ++j) {
                float x = acc[i][j][r] + av4[j];
                s = fmaf(g4[j], tanh_fast(x), s);
            }
            s_ir[i][r] = s;
        }
    }
    #pragma unroll
    for (int off = 8; off; off >>= 1) {
        #pragma unroll
        for (int i = 0; i < 4; ++i)
            #pragma unroll
            for (int r = 0; r < 4; ++r)
                s_ir[i][r] += __shfl_xor(s_ir[i][r], off, 16);
    }
    if (l15 == 0) {
        #pragma unroll
        for (int i = 0; i < 4; ++i)
            #pragma unroll
            for (int r = 0; r < 4; ++r)
                atomicAdd(&sred[wm * 64 + i * 16 + q * 4 + r], s_ir[i][r]);
    }
    __syncthreads();
    if (tid < 128) atomicAdd(&score[b * TT_SEQ + t0 + tid], sred[tid]);
}

// ---------------------------------------------------------------------------
// K5: masked, scaled softmax over T per b -> w; also zero c_v
// ---------------------------------------------------------------------------
__global__ __launch_bounds__(256) void k_softmax(const float* __restrict__ score,
                                                 const int* __restrict__ lens,
                                                 float* __restrict__ w_out,
                                                 float* __restrict__ c_v) {
    int b = blockIdx.x;
    int len = lens[b];
    __shared__ float red[4];
    float vals[8];
    float m = -INFINITY;
    #pragma unroll
    for (int i = 0; i < 8; ++i) {
        int t = threadIdx.x + i * 256;
        float s = (t < len) ? 2.0f * score[b * TT_SEQ + t] : -INFINITY;
        vals[i] = s;
        m = fmaxf(m, s);
    }
    #pragma unroll
    for (int off = 32; off; off >>= 1) m = fmaxf(m, __shfl_xor(m, off, 64));
    if ((threadIdx.x & 63) == 0) red[threadIdx.x >> 6] = m;
    __syncthreads();
    m = fmaxf(fmaxf(red[0], red[1]), fmaxf(red[2], red[3]));
    __syncthreads();
    float sum = 0.0f;
    #pragma unroll
    for (int i = 0; i < 8; ++i) {
        float e = expf(vals[i] - m);
        vals[i] = e;
        sum += e;
    }
    #pragma unroll
    for (int off = 32; off; off >>= 1) sum += __shfl_xor(sum, off, 64);
    if ((threadIdx.x & 63) == 0) red[threadIdx.x >> 6] = sum;
    __syncthreads();
    sum = red[0] + red[1] + red[2] + red[3];
    float inv = 1.0f / sum;
    #pragma unroll
    for (int i = 0; i < 8; ++i) w_out[b * TT_SEQ + threadIdx.x + i * 256] = vals[i] * inv;
    for (int i = threadIdx.x; i < EPROJS; i += 256) c_v[b * EPROJS + i] = 0.0f;
}

// ---------------------------------------------------------------------------
// K6: context from fp32 enc; 32 t-chunks of 64
// ---------------------------------------------------------------------------
__global__ __launch_bounds__(256) void k_ctx64(const float* __restrict__ enc,
                                               const float* __restrict__ w,
                                               const int* __restrict__ lens,
                                               float* __restrict__ c_v) {
    int b = blockIdx.y;
    int t0 = blockIdx.x * 64;
    if (t0 >= lens[b]) return;
    __shared__ float wsh[64];
    if (threadIdx.x < 64) wsh[threadIdx.x] = w[b * TT_SEQ + t0 + threadIdx.x];
    __syncthreads();
    const float* base = enc + ((size_t)b * TT_SEQ + t0) * EPROJS;
    float a0 = 0.f, a1 = 0.f;
    for (int t = 0; t < 64; ++t) {
        float wt = wsh[t];
        a0 = fmaf(wt, base[(size_t)t * EPROJS + threadIdx.x], a0);
        a1 = fmaf(wt, base[(size_t)t * EPROJS + threadIdx.x + 256], a1);
    }
    atomicAdd(&c_v[b * EPROJS + threadIdx.x], a0);
    atomicAdd(&c_v[b * EPROJS + threadIdx.x + 256], a1);
}

// ---------------------------------------------------------------------------
// Fallback fp32 kernels (round-1 validated), used only if ws too small
// ---------------------------------------------------------------------------
__global__ __launch_bounds__(256) void k_conv_fb(const float* __restrict__ att_prev,
                                                 const float* __restrict__ conv_w,
                                                 float* __restrict__ feat) {
    int b = blockIdx.x >> 5;
    int c = blockIdx.x & 31;
    __shared__ float row[TT_SEQ + 2 * FILT];
    __shared__ float wsh[KCONV];
    __shared__ float red[4];
    for (int i = threadIdx.x; i < TT_SEQ + 2 * FILT; i += 256) {
        int t = i - FILT;
        row[i] = (t >= 0 && t < TT_SEQ) ? att_prev[b * TT_SEQ + t] : 0.0f;
    }
    for (int i = threadIdx.x; i < KCONV; i += 256) wsh[i] = conv_w[c * KCONV + i];
    __syncthreads();
    float m = 0.0f;
    for (int t = threadIdx.x; t < TT_SEQ; t += 256) {
        float s = 0.0f;
        #pragma unroll 4
        for (int k = 0; k < KCONV; ++k) s = fmaf(wsh[k], row[t + k], s);
        m = fmaxf(m, s);
    }
    #pragma unroll
    for (int off = 32; off; off >>= 1) m = fmaxf(m, __shfl_xor(m, off, 64));
    if ((threadIdx.x & 63) == 0) red[threadIdx.x >> 6] = m;
    __syncthreads();
    if (threadIdx.x == 0) {
        m = fmaxf(fmaxf(red[0], red[1]), fmaxf(red[2], red[3]));
        feat[b * NCH + c] = m;
    }
}

__global__ __launch_bounds__(256) void k_lstm(const float* __restrict__ feat,
                                              const float* __restrict__ att_h,
                                              const float* __restrict__ att_c,
                                              const float* __restrict__ W_ih,
                                              const float* __restrict__ W_hh,
                                              const float* __restrict__ b_ih,
                                              const float* __restrict__ b_hh,
                                              float* __restrict__ h_out,
                                              float* __restrict__ c_out) {
    int b = blockIdx.x;
    __shared__ float fsh[NCH];
    __shared__ float hsh[ATT];
    __shared__ float gsh[G4];
    if (threadIdx.x < NCH) fsh[threadIdx.x] = feat[b * NCH + threadIdx.x];
    for (int i = threadIdx.x; i < ATT; i += 256) hsh[i] = att_h[b * ATT + i];
    __syncthreads();
    for (int j = threadIdx.x; j < G4; j += 256) {
        float acc = b_ih[j] + b_hh[j];
        const float* wi = W_ih + (size_t)j * NCH;
        #pragma unroll
        for (int c = 0; c < NCH; ++c) acc = fmaf(fsh[c], wi[c], acc);
        const float* wh = W_hh + (size_t)j * ATT;
        for (int a = 0; a < ATT; a += 4) {
            float4 w4 = *(const float4*)(wh + a);
            acc = fmaf(hsh[a + 0], w4.x, acc);
            acc = fmaf(hsh[a + 1], w4.y, acc);
            acc = fmaf(hsh[a + 2], w4.z, acc);
            acc = fmaf(hsh[a + 3], w4.w, acc);
        }
        gsh[j] = acc;
    }
    __syncthreads();
    for (int a = threadIdx.x; a < ATT; a += 256) {
        float ig = gsh[a], fg = gsh[ATT + a], gg = gsh[2 * ATT + a], og = gsh[3 * ATT + a];
        float si = 1.0f / (1.0f + expf(-ig));
        float sf = 1.0f / (1.0f + expf(-fg));
        float so = 1.0f / (1.0f + expf(-og));
        float cn = sf * att_c[b * ATT + a] + si * tanhf(gg);
        float hn = so * tanhf(cn);
        c_out[b * ATT + a] = cn;
        h_out[b * ATT + a] = hn;
    }
}

__global__ __launch_bounds__(256) void k_addvec(const float* __restrict__ dec_z,
                                                const float* __restrict__ h_new,
                                                const float* __restrict__ U_w,
                                                const float* __restrict__ U_b,
                                                const float* __restrict__ W_w,
                                                const float* __restrict__ W_b,
                                                const float* __restrict__ V_b,
                                                float* __restrict__ add_vec) {
    int b = blockIdx.x;
    __shared__ float zsh[ATT];
    __shared__ float hsh[ATT];
    for (int i = threadIdx.x; i < ATT; i += 256) {
        zsh[i] = dec_z[b * ATT + i];
        hsh[i] = h_new[b * ATT + i];
    }
    __syncthreads();
    for (int a = threadIdx.x; a < ATT; a += 256) {
        float acc = U_b[a] + W_b[a] + V_b[a];
        for (int d = 0; d < ATT; ++d) {
            acc = fmaf(zsh[d], U_w[(size_t)d * ATT + a], acc);
            acc = fmaf(hsh[d], W_w[(size_t)d * ATT + a], acc);
        }
        add_vec[b * ATT + a] = acc;
    }
}

#define TTILE 16
#define SR 516
__global__ __launch_bounds__(256) void k_score(const float* __restrict__ enc,
                                               const float* __restrict__ V_w,
                                               const float* __restrict__ add_vec,
                                               const float* __restrict__ g_w,
                                               const float* __restrict__ g_b,
                                               const int* __restrict__ lens,
                                               float* __restrict__ score) {
    int b = blockIdx.y;
    int t0 = blockIdx.x * TTILE;
    int len = lens[b];
    if (t0 >= len) return;
    __shared__ float enc_t[TTILE * SR];
    __shared__ float ash[ATT];
    __shared__ float gwsh[ATT];
    const float* src = enc + ((size_t)b * TT_SEQ + t0) * EPROJS;
    for (int i = threadIdx.x; i < TTILE * 128; i += 256) {
        int r = i >> 7, c4 = (i & 127) << 2;
        *(float4*)(enc_t + r * SR + c4) = *(const float4*)(src + (size_t)r * EPROJS + c4);
    }
    for (int i = threadIdx.x; i < ATT; i += 256) {
        ash[i] = add_vec[b * ATT + i];
        gwsh[i] = g_w[i];
    }
    __syncthreads();
    int t = threadIdx.x >> 4;
    int al = threadIdx.x & 15;
    const float* er = enc_t + t * SR;
    float sc = 0.0f;
    #pragma unroll
    for (int c = 0; c < 2; ++c) {
        float4 acc0 = {0, 0, 0, 0}, acc1 = {0, 0, 0, 0}, acc2 = {0, 0, 0, 0}, acc3 = {0, 0, 0, 0};
        int abase = c * 256 + al * 4;
        const float* vp = V_w + abase;
        for (int e = 0; e < EPROJS; ++e) {
            float s = er[e];
            const float* rowp = vp + (size_t)e * ATT;
            float4 w0 = *(const float4*)(rowp);
            float4 w1 = *(const float4*)(rowp + 64);
            float4 w2 = *(const float4*)(rowp + 128);
            float4 w3 = *(const float4*)(rowp + 192);
            acc0.x = fmaf(s, w0.x, acc0.x); acc0.y = fmaf(s, w0.y, acc0.y);
            acc0.z = fmaf(s, w0.z, acc0.z); acc0.w = fmaf(s, w0.w, acc0.w);
            acc1.x = fmaf(s, w1.x, acc1.x); acc1.y = fmaf(s, w1.y, acc1.y);
            acc1.z = fmaf(s, w1.z, acc1.z); acc1.w = fmaf(s, w1.w, acc1.w);
            acc2.x = fmaf(s, w2.x, acc2.x); acc2.y = fmaf(s, w2.y, acc2.y);
            acc2.z = fmaf(s, w2.z, acc2.z); acc2.w = fmaf(s, w2.w, acc2.w);
            acc3.x = fmaf(s, w3.x, acc3.x); acc3.y = fmaf(s, w3.y, acc3.y);
            acc3.z = fmaf(s, w3.z, acc3.z); acc3.w = fmaf(s, w3.w, acc3.w);
        }
        float av[16] = {acc0.x, acc0.y, acc0.z, acc0.w,
                        acc1.x, acc1.y, acc1.z, acc1.w,
                        acc2.x, acc2.y, acc2.z, acc2.w,
                        acc3.x, acc3.y, acc3.z, acc3.w};
        #pragma unroll
        for (int k = 0; k < 16; ++k) {
            int a = abase + (k >> 2) * 64 + (k & 3);
            sc = fmaf(gwsh[a], tanhf(av[k] + ash[a]), sc);
        }
    }
    #pragma unroll
    for (int off = 8; off; off >>= 1) sc += __shfl_xor(sc, off, 16);
    if (al == 0) score[b * TT_SEQ + t0 + t] = sc + g_b[0];
}

// ---------------------------------------------------------------------------
extern "C" void kernel_launch(void* const* d_in, const int* in_sizes, int n_in,
                              void* d_out, int out_size, void* d_ws, size_t ws_size,
                              hipStream_t stream) {
    const float* enc      = (const float*)d_in[0];
    const int*   lens     = (const int*)d_in[1];
    const float* dec_z    = (const float*)d_in[2];
    const float* att_prev = (const float*)d_in[3];
    const float* att_h    = (const float*)d_in[4];
    const float* att_c    = (const float*)d_in[5];
    const float* W_w      = (const float*)d_in[6];
    const float* W_b      = (const float*)d_in[7];
    const float* V_w      = (const float*)d_in[8];
    const float* V_b      = (const float*)d_in[9];
    const float* U_w      = (const float*)d_in[10];
    const float* U_b      = (const float*)d_in[11];
    const float* g_w      = (const float*)d_in[12];
    const float* g_b      = (const float*)d_in[13];
    const float* conv_w   = (const float*)d_in[14];
    const float* W_ih     = (const float*)d_in[15];
    const float* W_hh     = (const float*)d_in[16];
    const float* b_ih     = (const float*)d_in[17];
    const float* b_hh     = (const float*)d_in[18];

    float* out   = (float*)d_out;
    float* c_v   = out;
    float* w_out = out + BB * EPROJS;
    float* h_out = w_out + BB * TT_SEQ;
    float* c_out = h_out + BB * ATT;

    // workspace layout (fast path): vwt bf16 + feat + add_vec + score + gates
    const size_t need = (size_t)ATT * EPROJS * 2 +
                        (size_t)(1024 + BB * ATT + BB * TT_SEQ + BB * G4) * sizeof(float);

    if (ws_size >= need) {
        // ---- fast path: 6 launches ----
        ushort_t* vwt  = (ushort_t*)d_ws;
        float* feat    = (float*)(vwt + (size_t)ATT * EPROJS);
        float* add_vec = feat + 1024;
        float* score   = add_vec + BB * ATT;
        float* gates   = score + BB * TT_SEQ;

        k_pre<<<dim3(1024 + 64), dim3(256), 0, stream>>>(att_prev, conv_w, feat,
                                                         V_w, vwt, U_b, W_b, V_b,
                                                         add_vec, score);
        k_gates<<<dim3(G4 / 8), dim3(256), 0, stream>>>(feat, att_h, W_ih, W_hh,
                                                        b_ih, b_hh, gates);
        k_hz<<<dim3(16, 8), dim3(256), 0, stream>>>(gates, att_c, dec_z, U_w, W_w,
                                                    h_out, c_out, add_vec);
        k_gemm_score3<<<dim3(512, 4), dim3(256), 0, stream>>>(enc, vwt, add_vec, g_w,
                                                              lens, score);
        k_softmax<<<dim3(BB), dim3(256), 0, stream>>>(score, lens, w_out, c_v);
        k_ctx64<<<dim3(32, BB), dim3(256), 0, stream>>>(enc, w_out, lens, c_v);
    } else {
        // ---- fallback: fp32 path ----
        float* ws      = (float*)d_ws;
        float* feat    = ws;
        float* add_vec = ws + 1024;
        float* score   = ws + 1024 + BB * ATT;

        k_conv_fb<<<dim3(BB * NCH), dim3(256), 0, stream>>>(att_prev, conv_w, feat);
        k_lstm<<<dim3(BB), dim3(256), 0, stream>>>(feat, att_h, att_c, W_ih, W_hh,
                                                   b_ih, b_hh, h_out, c_out);
        k_addvec<<<dim3(BB), dim3(256), 0, stream>>>(dec_z, h_out, U_w, U_b, W_w, W_b,
                                                     V_b, add_vec);
        k_score<<<dim3(TT_SEQ / TTILE, BB), dim3(256), 0, stream>>>(enc, V_w, add_vec,
                                                                    g_w, g_b, lens, score);
        k_softmax<<<dim3(BB), dim3(256), 0, stream>>>(score, lens, w_out, c_v);
        k_ctx64<<<dim3(32, BB), dim3(256), 0, stream>>>(enc, w_out, lens, c_v);
    }
}

// Round 7
// 324.528 us; speedup vs baseline: 1.1041x; 1.1041x over previous
//
#include <hip/hip_runtime.h>
#include <math.h>

// Problem constants (fixed by the reference)
#define BB 32
#define TT_SEQ 2048
#define EPROJS 512
#define ATT 512
#define NCH 32
#define FILT 100
#define KCONV 201   // 2*FILT+1
#define G4 2048     // 4*ATT

typedef unsigned short ushort_t;
typedef unsigned int uint_t;
typedef __attribute__((ext_vector_type(8))) short bf16x8_t;
typedef __attribute__((ext_vector_type(4))) float f32x4_t;

__device__ inline ushort_t f2bf(float f) {
    uint_t u = __float_as_uint(f);
    uint_t r = (u + 0x7fffu + ((u >> 16) & 1u)) >> 16;   // RNE
    return (ushort_t)r;
}

__device__ inline float tanh_fast(float x) {
    float e = __expf(2.0f * x);
    return 1.0f - 2.0f / (e + 1.0f);   // exact at +/-inf saturation
}

// ---------------------------------------------------------------------------
// K_pre: branched grid. Blocks 0..1023: location conv+relu+maxpool -> feat.
// Blocks 1024..1087: V_w transpose->bf16 + add_vec bias init.
// ---------------------------------------------------------------------------
__global__ __launch_bounds__(256) void k_pre(const float* __restrict__ att_prev,
                                             const float* __restrict__ conv_w,
                                             float* __restrict__ feat,
                                             const float* __restrict__ vw,
                                             ushort_t* __restrict__ vwt,
                                             const float* __restrict__ U_b,
                                             const float* __restrict__ W_b,
                                             const float* __restrict__ V_b,
                                             float* __restrict__ add_vec) {
    __shared__ __align__(16) float shbuf[64 * 65];   // 16.6 KB, both branches
    __shared__ float red[4];
    if (blockIdx.x < 1024) {
        // ---- conv branch: sliding register window, 8 t per thread ----
        int b = blockIdx.x >> 5;
        int c = blockIdx.x & 31;
        float* row = shbuf;                          // needs 2256 floats
        for (int i = threadIdx.x; i < TT_SEQ + 2 * FILT + 8; i += 256) {
            int t = i - FILT;
            row[i] = (t >= 0 && t < TT_SEQ) ? att_prev[b * TT_SEQ + t] : 0.0f;
        }
        __syncthreads();
        const float* cw = conv_w + c * KCONV;        // block-uniform -> scalar loads
        int t0 = threadIdx.x * 8;
        float acc[8] = {0.f, 0.f, 0.f, 0.f, 0.f, 0.f, 0.f, 0.f};
        float4 r0 = *(const float4*)(row + t0);
        float4 r1 = *(const float4*)(row + t0 + 4);
        float r[8] = {r0.x, r0.y, r0.z, r0.w, r1.x, r1.y, r1.z, r1.w};
        for (int k = 0; k < 200; k += 8) {
            float4 n0 = *(const float4*)(row + t0 + k + 8);
            float4 n1 = *(const float4*)(row + t0 + k + 12);
            float nn[8] = {n0.x, n0.y, n0.z, n0.w, n1.x, n1.y, n1.z, n1.w};
            #pragma unroll
            for (int kk = 0; kk < 8; ++kk) {
                float w = cw[k + kk];
                #pragma unroll
                for (int i = 0; i < 8; ++i) {
                    float rv = (kk + i < 8) ? r[kk + i] : nn[kk + i - 8];
                    acc[i] = fmaf(w, rv, acc[i]);
                }
            }
            #pragma unroll
            for (int i = 0; i < 8; ++i) r[i] = nn[i];
        }
        float wlast = cw[200];
        #pragma unroll
        for (int i = 0; i < 8; ++i) acc[i] = fmaf(wlast, r[i], acc[i]);
        float m = 0.0f;  // relu floor
        #pragma unroll
        for (int i = 0; i < 8; ++i) m = fmaxf(m, acc[i]);
        #pragma unroll
        for (int off = 32; off; off >>= 1) m = fmaxf(m, __shfl_xor(m, off, 64));
        if ((threadIdx.x & 63) == 0) red[threadIdx.x >> 6] = m;
        __syncthreads();
        if (threadIdx.x == 0) {
            m = fmaxf(fmaxf(red[0], red[1]), fmaxf(red[2], red[3]));
            feat[b * NCH + c] = m;
        }
    } else {
        // ---- cvtw branch: V_w transpose->bf16; bias init ----
        int id = blockIdx.x - 1024;                  // 0..63
        int eb = (id & 7) * 64, ab = (id >> 3) * 64;
        float (*tile)[65] = (float (*)[65])shbuf;
        for (int it = 0; it < 16; ++it) {
            int idx = threadIdx.x + it * 256;
            int r = idx >> 6, c = idx & 63;
            tile[r][c] = vw[(size_t)(eb + r) * ATT + ab + c];
        }
        __syncthreads();
        for (int it = 0; it < 16; ++it) {
            int idx = threadIdx.x + it * 256;
            int r = idx >> 6, c = idx & 63;
            vwt[(size_t)(ab + r) * EPROJS + eb + c] = f2bf(tile[c][r]);
        }
        int i = id * 256 + threadIdx.x;              // 0..16383
        int a = i & 511;
        add_vec[i] = U_b[a] + W_b[a] + V_b[a];
    }
}

// ---------------------------------------------------------------------------
// K2: gates[b][j] = biases + feat@W_ih[j,:] + att_h@W_hh[j,:]
// ---------------------------------------------------------------------------
#define HP 518
__global__ __launch_bounds__(256) void k_gates(const float* __restrict__ feat,
                                               const float* __restrict__ att_h,
                                               const float* __restrict__ W_ih,
                                               const float* __restrict__ W_hh,
                                               const float* __restrict__ b_ih,
                                               const float* __restrict__ b_hh,
                                               float* __restrict__ gates) {
    __shared__ float hsh[32 * HP];
    __shared__ float fsh[32 * 33];
    int tid = threadIdx.x;
    for (int i = tid; i < 32 * 512; i += 256) {
        int r = i >> 9, c = i & 511;
        hsh[r * HP + c] = att_h[i];
    }
    for (int i = tid; i < 1024; i += 256) fsh[(i >> 5) * 33 + (i & 31)] = feat[i];
    __syncthreads();
    int jl = tid >> 5, b = tid & 31;
    int j = blockIdx.x * 8 + jl;
    float acc = b_ih[j] + b_hh[j];
    const float4* wi = (const float4*)(W_ih + (size_t)j * NCH);
    #pragma unroll
    for (int k4 = 0; k4 < 8; ++k4) {
        float4 w = wi[k4];
        const float* f = fsh + b * 33 + k4 * 4;
        acc = fmaf(w.x, f[0], acc);
        acc = fmaf(w.y, f[1], acc);
        acc = fmaf(w.z, f[2], acc);
        acc = fmaf(w.w, f[3], acc);
    }
    const float4* wh = (const float4*)(W_hh + (size_t)j * ATT);
    float a0 = 0.f, a1 = 0.f, a2 = 0.f, a3 = 0.f;
    #pragma unroll 8
    for (int k4 = 0; k4 < 128; ++k4) {
        float4 w = wh[k4];
        float2 h0 = *(const float2*)(hsh + b * HP + k4 * 4);
        float2 h1 = *(const float2*)(hsh + b * HP + k4 * 4 + 2);
        a0 = fmaf(w.x, h0.x, a0);
        a1 = fmaf(w.y, h0.y, a1);
        a2 = fmaf(w.z, h1.x, a2);
        a3 = fmaf(w.w, h1.y, a3);
    }
    gates[(size_t)b * G4 + j] = acc + ((a0 + a1) + (a2 + a3));
}

// ---------------------------------------------------------------------------
// K3: fused LSTM pointwise + add_vec split-K GEMM.
// ---------------------------------------------------------------------------
__global__ __launch_bounds__(256) void k_hz(const float* __restrict__ gates,
                                            const float* __restrict__ att_c,
                                            const float* __restrict__ dec_z,
                                            const float* __restrict__ U_w,
                                            const float* __restrict__ W_w,
                                            float* __restrict__ h_out,
                                            float* __restrict__ c_out,
                                            float* __restrict__ add_vec) {
    int a0 = blockIdx.x * 32;
    int k0 = blockIdx.y * 64;
    __shared__ float zsh[32 * 65];
    __shared__ float hsh[32 * 65];
    __shared__ float us[64 * 33];
    __shared__ float ws2[64 * 33];
    int tid = threadIdx.x;
    for (int i = tid; i < 2048; i += 256) {
        int b = i >> 6, d = i & 63;
        int idx = b * ATT + k0 + d;
        const float* g = gates + (size_t)b * G4 + k0 + d;
        float ig = g[0], fg = g[ATT], gg = g[2 * ATT], og = g[3 * ATT];
        float si = 1.0f / (1.0f + expf(-ig));
        float sf = 1.0f / (1.0f + expf(-fg));
        float so = 1.0f / (1.0f + expf(-og));
        float cn = sf * att_c[idx] + si * tanhf(gg);
        float hn = so * tanhf(cn);
        hsh[b * 65 + d] = hn;
        if (blockIdx.x == 0) { c_out[idx] = cn; h_out[idx] = hn; }
        zsh[b * 65 + d] = dec_z[idx];
        int dr = i >> 5, c = i & 31;
        us[dr * 33 + c] = U_w[(size_t)(k0 + dr) * ATT + a0 + c];
        ws2[dr * 33 + c] = W_w[(size_t)(k0 + dr) * ATT + a0 + c];
    }
    __syncthreads();
    int al = tid >> 5, b = tid & 31;
    float acc[4] = {0.f, 0.f, 0.f, 0.f};
    for (int d = 0; d < 64; ++d) {
        float zv = zsh[b * 65 + d];
        float hv = hsh[b * 65 + d];
        #pragma unroll
        for (int m = 0; m < 4; ++m) {
            int a = al + 8 * m;
            acc[m] = fmaf(zv, us[d * 33 + a], acc[m]);
            acc[m] = fmaf(hv, ws2[d * 33 + a], acc[m]);
        }
    }
    #pragma unroll
    for (int m = 0; m < 4; ++m)
        atomicAdd(&add_vec[(size_t)b * ATT + a0 + al + 8 * m], acc[m]);
}

// ---------------------------------------------------------------------------
// K4: fused bf16 MFMA GEMM + score epilogue. FULL-N (A fetched from HBM once,
// ~56 MB total) with fixed occupancy: 1024 threads = 16 waves (2m x 8n),
// per-wave 64x64 -> acc[4][4] = 64 acc regs; __launch_bounds__(1024,4) caps
// VGPR at 128 -> 4 waves/SIMD (2x the R5 variant's residency).
// LDS: sA 16 KB + sB 64 KB = 80 KB. Direct score write (no global atomics).
// grid = 512 m-tiles.
// ---------------------------------------------------------------------------
__global__ __launch_bounds__(1024, 4) void k_gemm_score4(
        const float* __restrict__ enc,
        const ushort_t* __restrict__ Btbf,
        const float* __restrict__ add_vec,
        const float* __restrict__ g_w,
        const int* __restrict__ lens,
        float* __restrict__ score) {
    int mtile = blockIdx.x;
    int b = mtile >> 4;
    int t0 = (mtile & 15) * 128;
    if (t0 >= lens[b]) return;          // fully masked tile: score never read

    __shared__ __align__(16) ushort_t sA[128 * 64];   // 16 KB
    __shared__ __align__(16) ushort_t sB[512 * 64];   // 64 KB

    int tid = threadIdx.x;
    int lane = tid & 63;
    int wave = tid >> 6;                // 0..15
    int wm = wave & 1, wn = wave >> 1;  // 2 m-slices x 8 n-slices
    int q = lane >> 4, l15 = lane & 15;

    const float* Ag = enc + (size_t)mtile * 128 * EPROJS;

    f32x4_t acc[4][4];
    #pragma unroll
    for (int i = 0; i < 4; ++i)
        #pragma unroll
        for (int j = 0; j < 4; ++j) acc[i][j] = (f32x4_t){0.f, 0.f, 0.f, 0.f};

    for (int kc = 0; kc < 8; ++kc) {
        __syncthreads();
        // B tile via DMA: 512 rows x 8 kq-groups = 4096 groups, 4 per thread
        #pragma unroll
        for (int it = 0; it < 4; ++it) {
            int g = tid + it * 1024;
            int n = g >> 3;
            int kq = g & 7;
            int kqs = kq ^ (n & 7);
            __builtin_amdgcn_global_load_lds(
                (const __attribute__((address_space(1))) void*)(Btbf + (size_t)n * EPROJS + kc * 64 + kqs * 8),
                (__attribute__((address_space(3))) void*)(sB + g * 8), 16, 0, 0);
        }
        // A tile: 1024 groups, 1 per thread: fp32 load -> bf16 RNE -> LDS
        {
            int g = tid;
            int m = g >> 3;
            int kq = g & 7;
            int kqs = kq ^ (m & 7);
            const float* src = Ag + (size_t)m * EPROJS + kc * 64 + kqs * 8;
            float4 v0 = *(const float4*)(src);
            float4 v1 = *(const float4*)(src + 4);
            bf16x8_t o;
            o[0] = (short)f2bf(v0.x); o[1] = (short)f2bf(v0.y);
            o[2] = (short)f2bf(v0.z); o[3] = (short)f2bf(v0.w);
            o[4] = (short)f2bf(v1.x); o[5] = (short)f2bf(v1.y);
            o[6] = (short)f2bf(v1.z); o[7] = (short)f2bf(v1.w);
            *(bf16x8_t*)(sA + g * 8) = o;
        }
        __syncthreads();                       // drains vmcnt + lgkmcnt
        #pragma unroll
        for (int s = 0; s < 2; ++s) {
            bf16x8_t af[4], bfr[4];
            int kq = s * 4 + q;
            #pragma unroll
            for (int i = 0; i < 4; ++i) {
                int m = wm * 64 + i * 16 + l15;
                af[i] = *(const bf16x8_t*)(sA + (m * 8 + (kq ^ (m & 7))) * 8);
            }
            #pragma unroll
            for (int j = 0; j < 4; ++j) {
                int n = wn * 64 + j * 16 + l15;
                bfr[j] = *(const bf16x8_t*)(sB + (n * 8 + (kq ^ (n & 7))) * 8);
            }
            #pragma unroll
            for (int i = 0; i < 4; ++i)
                #pragma unroll
                for (int j = 0; j < 4; ++j)
                    acc[i][j] = __builtin_amdgcn_mfma_f32_16x16x32_bf16(af[i], bfr[j], acc[i][j], 0, 0, 0);
        }
    }

    // ---- epilogue: full score for 128 t, direct write --------------------
    float g4[4], av4[4];
    #pragma unroll
    for (int j = 0; j < 4; ++j) {
        int a = wn * 64 + j * 16 + l15;
        g4[j] = g_w[a];
        av4[j] = add_vec[b * ATT + a];
    }
    float s_ir[4][4];
    #pragma unroll
    for (int i = 0; i < 4; ++i) {
        #pragma unroll
        for (int r = 0; r < 4; ++r) {
            float s = 0.0f;
            #pragma unroll
            for (int j = 0; j < 4; ++j) {
                float x = acc[i][j][r] + av4[j];
                s = fmaf(g4[j], tanh_fast(x), s);
            }
            s_ir[i][r] = s;
        }
    }
    #pragma unroll
    for (int off = 8; off; off >>= 1) {
        #pragma unroll
        for (int i = 0; i < 4; ++i)
            #pragma unroll
            for (int r = 0; r < 4; ++r)
                s_ir[i][r] += __shfl_xor(s_ir[i][r], off, 16);
    }
    __syncthreads();                 // done reading sA -> reuse as sred
    float* sred = (float*)sA;
    if (tid < 128) sred[tid] = 0.0f;
    __syncthreads();
    if (l15 == 0) {
        #pragma unroll
        for (int i = 0; i < 4; ++i)
            #pragma unroll
            for (int r = 0; r < 4; ++r)
                atomicAdd(&sred[wm * 64 + i * 16 + q * 4 + r], s_ir[i][r]);
    }
    __syncthreads();
    if (tid < 128) score[b * TT_SEQ + t0 + tid] = sred[tid];
}

// ---------------------------------------------------------------------------
// K5: masked, scaled softmax over T per b -> w; also zero c_v
// ---------------------------------------------------------------------------
__global__ __launch_bounds__(256) void k_softmax(const float* __restrict__ score,
                                                 const int* __restrict__ lens,
                                                 float* __restrict__ w_out,
                                                 float* __restrict__ c_v) {
    int b = blockIdx.x;
    int len = lens[b];
    __shared__ float red[4];
    float vals[8];
    float m = -INFINITY;
    #pragma unroll
    for (int i = 0; i < 8; ++i) {
        int t = threadIdx.x + i * 256;
        float s = (t < len) ? 2.0f * score[b * TT_SEQ + t] : -INFINITY;
        vals[i] = s;
        m = fmaxf(m, s);
    }
    #pragma unroll
    for (int off = 32; off; off >>= 1) m = fmaxf(m, __shfl_xor(m, off, 64));
    if ((threadIdx.x & 63) == 0) red[threadIdx.x >> 6] = m;
    __syncthreads();
    m = fmaxf(fmaxf(red[0], red[1]), fmaxf(red[2], red[3]));
    __syncthreads();
    float sum = 0.0f;
    #pragma unroll
    for (int i = 0; i < 8; ++i) {
        float e = expf(vals[i] - m);
        vals[i] = e;
        sum += e;
    }
    #pragma unroll
    for (int off = 32; off; off >>= 1) sum += __shfl_xor(sum, off, 64);
    if ((threadIdx.x & 63) == 0) red[threadIdx.x >> 6] = sum;
    __syncthreads();
    sum = red[0] + red[1] + red[2] + red[3];
    float inv = 1.0f / sum;
    #pragma unroll
    for (int i = 0; i < 8; ++i) w_out[b * TT_SEQ + threadIdx.x + i * 256] = vals[i] * inv;
    for (int i = threadIdx.x; i < EPROJS; i += 256) c_v[b * EPROJS + i] = 0.0f;
}

// ---------------------------------------------------------------------------
// K6: context from fp32 enc; 32 t-chunks of 64
// ---------------------------------------------------------------------------
__global__ __launch_bounds__(256) void k_ctx64(const float* __restrict__ enc,
                                               const float* __restrict__ w,
                                               const int* __restrict__ lens,
                                               float* __restrict__ c_v) {
    int b = blockIdx.y;
    int t0 = blockIdx.x * 64;
    if (t0 >= lens[b]) return;
    __shared__ float wsh[64];
    if (threadIdx.x < 64) wsh[threadIdx.x] = w[b * TT_SEQ + t0 + threadIdx.x];
    __syncthreads();
    const float* base = enc + ((size_t)b * TT_SEQ + t0) * EPROJS;
    float a0 = 0.f, a1 = 0.f;
    for (int t = 0; t < 64; ++t) {
        float wt = wsh[t];
        a0 = fmaf(wt, base[(size_t)t * EPROJS + threadIdx.x], a0);
        a1 = fmaf(wt, base[(size_t)t * EPROJS + threadIdx.x + 256], a1);
    }
    atomicAdd(&c_v[b * EPROJS + threadIdx.x], a0);
    atomicAdd(&c_v[b * EPROJS + threadIdx.x + 256], a1);
}

// ---------------------------------------------------------------------------
// Fallback fp32 kernels (round-1 validated), used only if ws too small
// ---------------------------------------------------------------------------
__global__ __launch_bounds__(256) void k_conv_fb(const float* __restrict__ att_prev,
                                                 const float* __restrict__ conv_w,
                                                 float* __restrict__ feat) {
    int b = blockIdx.x >> 5;
    int c = blockIdx.x & 31;
    __shared__ float row[TT_SEQ + 2 * FILT];
    __shared__ float wsh[KCONV];
    __shared__ float red[4];
    for (int i = threadIdx.x; i < TT_SEQ + 2 * FILT; i += 256) {
        int t = i - FILT;
        row[i] = (t >= 0 && t < TT_SEQ) ? att_prev[b * TT_SEQ + t] : 0.0f;
    }
    for (int i = threadIdx.x; i < KCONV; i += 256) wsh[i] = conv_w[c * KCONV + i];
    __syncthreads();
    float m = 0.0f;
    for (int t = threadIdx.x; t < TT_SEQ; t += 256) {
        float s = 0.0f;
        #pragma unroll 4
        for (int k = 0; k < KCONV; ++k) s = fmaf(wsh[k], row[t + k], s);
        m = fmaxf(m, s);
    }
    #pragma unroll
    for (int off = 32; off; off >>= 1) m = fmaxf(m, __shfl_xor(m, off, 64));
    if ((threadIdx.x & 63) == 0) red[threadIdx.x >> 6] = m;
    __syncthreads();
    if (threadIdx.x == 0) {
        m = fmaxf(fmaxf(red[0], red[1]), fmaxf(red[2], red[3]));
        feat[b * NCH + c] = m;
    }
}

__global__ __launch_bounds__(256) void k_lstm(const float* __restrict__ feat,
                                              const float* __restrict__ att_h,
                                              const float* __restrict__ att_c,
                                              const float* __restrict__ W_ih,
                                              const float* __restrict__ W_hh,
                                              const float* __restrict__ b_ih,
                                              const float* __restrict__ b_hh,
                                              float* __restrict__ h_out,
                                              float* __restrict__ c_out) {
    int b = blockIdx.x;
    __shared__ float fsh[NCH];
    __shared__ float hsh[ATT];
    __shared__ float gsh[G4];
    if (threadIdx.x < NCH) fsh[threadIdx.x] = feat[b * NCH + threadIdx.x];
    for (int i = threadIdx.x; i < ATT; i += 256) hsh[i] = att_h[b * ATT + i];
    __syncthreads();
    for (int j = threadIdx.x; j < G4; j += 256) {
        float acc = b_ih[j] + b_hh[j];
        const float* wi = W_ih + (size_t)j * NCH;
        #pragma unroll
        for (int c = 0; c < NCH; ++c) acc = fmaf(fsh[c], wi[c], acc);
        const float* wh = W_hh + (size_t)j * ATT;
        for (int a = 0; a < ATT; a += 4) {
            float4 w4 = *(const float4*)(wh + a);
            acc = fmaf(hsh[a + 0], w4.x, acc);
            acc = fmaf(hsh[a + 1], w4.y, acc);
            acc = fmaf(hsh[a + 2], w4.z, acc);
            acc = fmaf(hsh[a + 3], w4.w, acc);
        }
        gsh[j] = acc;
    }
    __syncthreads();
    for (int a = threadIdx.x; a < ATT; a += 256) {
        float ig = gsh[a], fg = gsh[ATT + a], gg = gsh[2 * ATT + a], og = gsh[3 * ATT + a];
        float si = 1.0f / (1.0f + expf(-ig));
        float sf = 1.0f / (1.0f + expf(-fg));
        float so = 1.0f / (1.0f + expf(-og));
        float cn = sf * att_c[b * ATT + a] + si * tanhf(gg);
        float hn = so * tanhf(cn);
        c_out[b * ATT + a] = cn;
        h_out[b * ATT + a] = hn;
    }
}

__global__ __launch_bounds__(256) void k_addvec(const float* __restrict__ dec_z,
                                                const float* __restrict__ h_new,
                                                const float* __restrict__ U_w,
                                                const float* __restrict__ U_b,
                                                const float* __restrict__ W_w,
                                                const float* __restrict__ W_b,
                                                const float* __restrict__ V_b,
                                                float* __restrict__ add_vec) {
    int b = blockIdx.x;
    __shared__ float zsh[ATT];
    __shared__ float hsh[ATT];
    for (int i = threadIdx.x; i < ATT; i += 256) {
        zsh[i] = dec_z[b * ATT + i];
        hsh[i] = h_new[b * ATT + i];
    }
    __syncthreads();
    for (int a = threadIdx.x; a < ATT; a += 256) {
        float acc = U_b[a] + W_b[a] + V_b[a];
        for (int d = 0; d < ATT; ++d) {
            acc = fmaf(zsh[d], U_w[(size_t)d * ATT + a], acc);
            acc = fmaf(hsh[d], W_w[(size_t)d * ATT + a], acc);
        }
        add_vec[b * ATT + a] = acc;
    }
}

#define TTILE 16
#define SR 516
__global__ __launch_bounds__(256) void k_score(const float* __restrict__ enc,
                                               const float* __restrict__ V_w,
                                               const float* __restrict__ add_vec,
                                               const float* __restrict__ g_w,
                                               const float* __restrict__ g_b,
                                               const int* __restrict__ lens,
                                               float* __restrict__ score) {
    int b = blockIdx.y;
    int t0 = blockIdx.x * TTILE;
    int len = lens[b];
    if (t0 >= len) return;
    __shared__ float enc_t[TTILE * SR];
    __shared__ float ash[ATT];
    __shared__ float gwsh[ATT];
    const float* src = enc + ((size_t)b * TT_SEQ + t0) * EPROJS;
    for (int i = threadIdx.x; i < TTILE * 128; i += 256) {
        int r = i >> 7, c4 = (i & 127) << 2;
        *(float4*)(enc_t + r * SR + c4) = *(const float4*)(src + (size_t)r * EPROJS + c4);
    }
    for (int i = threadIdx.x; i < ATT; i += 256) {
        ash[i] = add_vec[b * ATT + i];
        gwsh[i] = g_w[i];
    }
    __syncthreads();
    int t = threadIdx.x >> 4;
    int al = threadIdx.x & 15;
    const float* er = enc_t + t * SR;
    float sc = 0.0f;
    #pragma unroll
    for (int c = 0; c < 2; ++c) {
        float4 acc0 = {0, 0, 0, 0}, acc1 = {0, 0, 0, 0}, acc2 = {0, 0, 0, 0}, acc3 = {0, 0, 0, 0};
        int abase = c * 256 + al * 4;
        const float* vp = V_w + abase;
        for (int e = 0; e < EPROJS; ++e) {
            float s = er[e];
            const float* rowp = vp + (size_t)e * ATT;
            float4 w0 = *(const float4*)(rowp);
            float4 w1 = *(const float4*)(rowp + 64);
            float4 w2 = *(const float4*)(rowp + 128);
            float4 w3 = *(const float4*)(rowp + 192);
            acc0.x = fmaf(s, w0.x, acc0.x); acc0.y = fmaf(s, w0.y, acc0.y);
            acc0.z = fmaf(s, w0.z, acc0.z); acc0.w = fmaf(s, w0.w, acc0.w);
            acc1.x = fmaf(s, w1.x, acc1.x); acc1.y = fmaf(s, w1.y, acc1.y);
            acc1.z = fmaf(s, w1.z, acc1.z); acc1.w = fmaf(s, w1.w, acc1.w);
            acc2.x = fmaf(s, w2.x, acc2.x); acc2.y = fmaf(s, w2.y, acc2.y);
            acc2.z = fmaf(s, w2.z, acc2.z); acc2.w = fmaf(s, w2.w, acc2.w);
            acc3.x = fmaf(s, w3.x, acc3.x); acc3.y = fmaf(s, w3.y, acc3.y);
            acc3.z = fmaf(s, w3.z, acc3.z); acc3.w = fmaf(s, w3.w, acc3.w);
        }
        float av[16] = {acc0.x, acc0.y, acc0.z, acc0.w,
                        acc1.x, acc1.y, acc1.z, acc1.w,
                        acc2.x, acc2.y, acc2.z, acc2.w,
                        acc3.x, acc3.y, acc3.z, acc3.w};
        #pragma unroll
        for (int k = 0; k < 16; ++k) {
            int a = abase + (k >> 2) * 64 + (k & 3);
            sc = fmaf(gwsh[a], tanhf(av[k] + ash[a]), sc);
        }
    }
    #pragma unroll
    for (int off = 8; off; off >>= 1) sc += __shfl_xor(sc, off, 16);
    if (al == 0) score[b * TT_SEQ + t0 + t] = sc + g_b[0];
}

// ---------------------------------------------------------------------------
extern "C" void kernel_launch(void* const* d_in, const int* in_sizes, int n_in,
                              void* d_out, int out_size, void* d_ws, size_t ws_size,
                              hipStream_t stream) {
    const float* enc      = (const float*)d_in[0];
    const int*   lens     = (const int*)d_in[1];
    const float* dec_z    = (const float*)d_in[2];
    const float* att_prev = (const float*)d_in[3];
    const float* att_h    = (const float*)d_in[4];
    const float* att_c    = (const float*)d_in[5];
    const float* W_w      = (const float*)d_in[6];
    const float* W_b      = (const float*)d_in[7];
    const float* V_w      = (const float*)d_in[8];
    const float* V_b      = (const float*)d_in[9];
    const float* U_w      = (const float*)d_in[10];
    const float* U_b      = (const float*)d_in[11];
    const float* g_w      = (const float*)d_in[12];
    const float* g_b      = (const float*)d_in[13];
    const float* conv_w   = (const float*)d_in[14];
    const float* W_ih     = (const float*)d_in[15];
    const float* W_hh     = (const float*)d_in[16];
    const float* b_ih     = (const float*)d_in[17];
    const float* b_hh     = (const float*)d_in[18];

    float* out   = (float*)d_out;
    float* c_v   = out;
    float* w_out = out + BB * EPROJS;
    float* h_out = w_out + BB * TT_SEQ;
    float* c_out = h_out + BB * ATT;

    // workspace layout (fast path): vwt bf16 + feat + add_vec + score + gates
    const size_t need = (size_t)ATT * EPROJS * 2 +
                        (size_t)(1024 + BB * ATT + BB * TT_SEQ + BB * G4) * sizeof(float);

    if (ws_size >= need) {
        // ---- fast path: 6 launches ----
        ushort_t* vwt  = (ushort_t*)d_ws;
        float* feat    = (float*)(vwt + (size_t)ATT * EPROJS);
        float* add_vec = feat + 1024;
        float* score   = add_vec + BB * ATT;
        float* gates   = score + BB * TT_SEQ;

        k_pre<<<dim3(1024 + 64), dim3(256), 0, stream>>>(att_prev, conv_w, feat,
                                                         V_w, vwt, U_b, W_b, V_b,
                                                         add_vec);
        k_gates<<<dim3(G4 / 8), dim3(256), 0, stream>>>(feat, att_h, W_ih, W_hh,
                                                        b_ih, b_hh, gates);
        k_hz<<<dim3(16, 8), dim3(256), 0, stream>>>(gates, att_c, dec_z, U_w, W_w,
                                                    h_out, c_out, add_vec);
        k_gemm_score4<<<dim3(512), dim3(1024), 0, stream>>>(enc, vwt, add_vec, g_w,
                                                            lens, score);
        k_softmax<<<dim3(BB), dim3(256), 0, stream>>>(score, lens, w_out, c_v);
        k_ctx64<<<dim3(32, BB), dim3(256), 0, stream>>>(enc, w_out, lens, c_v);
    } else {
        // ---- fallback: fp32 path ----
        float* ws      = (float*)d_ws;
        float* feat    = ws;
        float* add_vec = ws + 1024;
        float* score   = ws + 1024 + BB * ATT;

        k_conv_fb<<<dim3(BB * NCH), dim3(256), 0, stream>>>(att_prev, conv_w, feat);
        k_lstm<<<dim3(BB), dim3(256), 0, stream>>>(feat, att_h, att_c, W_ih, W_hh,
                                                   b_ih, b_hh, h_out, c_out);
        k_addvec<<<dim3(BB), dim3(256), 0, stream>>>(dec_z, h_out, U_w, U_b, W_w, W_b,
                                                     V_b, add_vec);
        k_score<<<dim3(TT_SEQ / TTILE, BB), dim3(256), 0, stream>>>(enc, V_w, add_vec,
                                                                    g_w, g_b, lens, score);
        k_softmax<<<dim3(BB), dim3(256), 0, stream>>>(score, lens, w_out, c_v);
        k_ctx64<<<dim3(32, BB), dim3(256), 0, stream>>>(enc, w_out, lens, c_v);
    }
}